// Round 1
// baseline (519.091 us; speedup 1.0000x reference)
//
#include <hip/hip_runtime.h>

// Stable stream compaction: y[:count] = x[x>0] in original order, y[count:]=0,
// y[out_size-1] = (float)count.
//
// 3-pass scan + scatter + tail zerofill. CHUNK elems per block.

#define BLOCK 256
#define CHUNK 4096           // 256 threads * 4 float4 sub-tiles * 4 elems
#define SCAN_THREADS 1024
#define SCAN_VPT 16          // supports up to 16384 blocks

__global__ void k_count(const float* __restrict__ x, int n, int* __restrict__ blockSums) {
    const int tid = threadIdx.x;
    const int base = blockIdx.x * CHUNK;
    int cnt = 0;
#pragma unroll
    for (int k = 0; k < 4; ++k) {
        const int i = base + k * 1024 + tid * 4;
        if (i + 3 < n) {
            const float4 v = *reinterpret_cast<const float4*>(x + i);
            cnt += (v.x > 0.f) + (v.y > 0.f) + (v.z > 0.f) + (v.w > 0.f);
        } else {
            for (int j = i; j < i + 4 && j < n; ++j) cnt += (x[j] > 0.f);
        }
    }
#pragma unroll
    for (int off = 32; off > 0; off >>= 1) cnt += __shfl_down(cnt, off, 64);
    __shared__ int lds[4];
    if ((tid & 63) == 0) lds[tid >> 6] = cnt;
    __syncthreads();
    if (tid == 0) blockSums[blockIdx.x] = lds[0] + lds[1] + lds[2] + lds[3];
}

// Single-block exclusive scan of blockSums (numBlocks <= SCAN_THREADS*SCAN_VPT).
__global__ void k_scan(int* __restrict__ sums, int numBlocks,
                       int* __restrict__ countOut, float* __restrict__ countOutF) {
    __shared__ int lds[32];
    const int tid  = threadIdx.x;
    const int lane = tid & 63;
    const int wave = tid >> 6;   // 16 waves

    int vals[SCAN_VPT];
    const int base = tid * SCAN_VPT;
    int local = 0;
#pragma unroll
    for (int j = 0; j < SCAN_VPT; ++j) {
        const int i = base + j;
        const int v = (i < numBlocks) ? sums[i] : 0;
        vals[j] = local;         // thread-local exclusive
        local += v;
    }
    // wave inclusive scan of per-thread totals
    int incl = local;
#pragma unroll
    for (int off = 1; off < 64; off <<= 1) {
        const int y = __shfl_up(incl, off, 64);
        if (lane >= off) incl += y;
    }
    if (lane == 63) lds[wave] = incl;
    __syncthreads();
    if (wave == 0 && lane < 16) {
        int w = lds[lane];
#pragma unroll
        for (int off = 1; off < 16; off <<= 1) {
            const int y = __shfl_up(w, off, 16);
            if ((lane & 15) >= off) w += y;
        }
        lds[16 + lane] = w;      // inclusive wave prefix
    }
    __syncthreads();
    const int waveEx   = (wave == 0) ? 0 : lds[16 + wave - 1];
    const int threadEx = waveEx + incl - local;
#pragma unroll
    for (int j = 0; j < SCAN_VPT; ++j) {
        const int i = base + j;
        if (i < numBlocks) sums[i] = threadEx + vals[j];
    }
    if (tid == SCAN_THREADS - 1) {
        const int total = waveEx + incl;
        *countOut  = total;
        *countOutF = (float)total;   // same round-to-nearest as numpy astype
    }
}

// exclusive block scan over 256 threads (4 waves); returns exclusive rank,
// sets *blockTotal. lds must have >= 9 ints.
__device__ __forceinline__ int block_scan_excl_256(int val, int* lds, int* blockTotal) {
    const int tid  = threadIdx.x;
    const int lane = tid & 63;
    const int wave = tid >> 6;
    int incl = val;
#pragma unroll
    for (int off = 1; off < 64; off <<= 1) {
        const int y = __shfl_up(incl, off, 64);
        if (lane >= off) incl += y;
    }
    if (lane == 63) lds[wave] = incl;
    __syncthreads();
    if (tid == 0) {
        const int s0 = lds[0], s1 = lds[1], s2 = lds[2], s3 = lds[3];
        lds[4] = 0; lds[5] = s0; lds[6] = s0 + s1; lds[7] = s0 + s1 + s2;
        lds[8] = s0 + s1 + s2 + s3;
    }
    __syncthreads();
    const int ex = lds[4 + wave] + incl - val;
    *blockTotal = lds[8];
    __syncthreads();   // protect lds reuse next iteration
    return ex;
}

__global__ void k_scatter(const float* __restrict__ x, int n,
                          const int* __restrict__ blockOffsets, float* __restrict__ y) {
    __shared__ int lds[9];
    const int tid  = threadIdx.x;
    const int base = blockIdx.x * CHUNK;
    int offset = blockOffsets[blockIdx.x];
#pragma unroll
    for (int k = 0; k < 4; ++k) {
        const int i = base + k * 1024 + tid * 4;
        float a0 = 0.f, a1 = 0.f, a2 = 0.f, a3 = 0.f;
        if (i + 3 < n) {
            const float4 v = *reinterpret_cast<const float4*>(x + i);
            a0 = v.x; a1 = v.y; a2 = v.z; a3 = v.w;
        } else {
            if (i + 0 < n) a0 = x[i + 0];
            if (i + 1 < n) a1 = x[i + 1];
            if (i + 2 < n) a2 = x[i + 2];
            if (i + 3 < n) a3 = x[i + 3];
        }
        const int m0 = a0 > 0.f, m1 = a1 > 0.f, m2 = a2 > 0.f, m3 = a3 > 0.f;
        int total;
        const int rank = block_scan_excl_256(m0 + m1 + m2 + m3, lds, &total);
        int o = offset + rank;
        if (m0) y[o++] = a0;
        if (m1) y[o++] = a1;
        if (m2) y[o++] = a2;
        if (m3) y[o++] = a3;
        offset += total;
    }
}

__global__ void k_zerofill(float* __restrict__ y, const int* __restrict__ count, int n) {
    const int i = (blockIdx.x * BLOCK + threadIdx.x) * 4;
    if (i >= n) return;
    const int c = *count;
    if (i + 4 <= c) return;                      // fully inside valid region
    const int start = (i > c) ? i : c;
    const int end   = (i + 4 < n) ? i + 4 : n;
    if (start == i && end == i + 4) {
        *reinterpret_cast<float4*>(y + i) = make_float4(0.f, 0.f, 0.f, 0.f);
    } else {
        for (int j = start; j < end; ++j) y[j] = 0.f;
    }
}

extern "C" void kernel_launch(void* const* d_in, const int* in_sizes, int n_in,
                              void* d_out, int out_size, void* d_ws, size_t ws_size,
                              hipStream_t stream) {
    const float* x = (const float*)d_in[0];
    float* y = (float*)d_out;
    const int n = in_sizes[0];

    int* blockSums = (int*)d_ws;
    const int numBlocks = (n + CHUNK - 1) / CHUNK;   // 16384 for N=64M
    int* countPtr = blockSums + numBlocks;

    k_count<<<numBlocks, BLOCK, 0, stream>>>(x, n, blockSums);
    k_scan<<<1, SCAN_THREADS, 0, stream>>>(blockSums, numBlocks,
                                           countPtr, y + (out_size - 1));
    k_scatter<<<numBlocks, BLOCK, 0, stream>>>(x, n, blockSums, y);
    const int zfBlocks = ((n + 3) / 4 + BLOCK - 1) / BLOCK;
    k_zerofill<<<zfBlocks, BLOCK, 0, stream>>>(y, countPtr, n);
}

// Round 2
// 504.386 us; speedup vs baseline: 1.0292x; 1.0292x over previous
//
#include <hip/hip_runtime.h>

// Stable stream compaction: y[:count] = x[x>0] in original order, y[count:]=0,
// y[out_size-1] = (float)count.
//
// 3-pass: per-block count -> single-block scan of block sums -> scatter via
// LDS staging (coalesced stores) -> tail zerofill.
//
// Layout: each thread owns 16 CONTIGUOUS elements (4 back-to-back float4
// loads). This keeps stable order with a single block scan per chunk and
// lets the compacted output leave via coalesced consecutive-lane stores.

#define BLOCK 256
#define VPT 16               // elems per thread (contiguous)
#define CHUNK (BLOCK * VPT)  // 4096
#define SCAN_THREADS 1024
#define SCAN_VPT 16          // scan kernel supports up to 16384 block sums

__global__ void k_count(const float* __restrict__ x, int n, int* __restrict__ blockSums) {
    const int tid = threadIdx.x;
    const long long tbase = (long long)blockIdx.x * CHUNK + tid * VPT;
    int cnt = 0;
    if (tbase + VPT <= n) {
#pragma unroll
        for (int k = 0; k < 4; ++k) {
            const float4 v = *reinterpret_cast<const float4*>(x + tbase + 4 * k);
            cnt += (v.x > 0.f) + (v.y > 0.f) + (v.z > 0.f) + (v.w > 0.f);
        }
    } else {
        for (long long j = tbase; j < tbase + VPT && j < n; ++j) cnt += (x[j] > 0.f);
    }
#pragma unroll
    for (int off = 32; off > 0; off >>= 1) cnt += __shfl_down(cnt, off, 64);
    __shared__ int lds[4];
    if ((tid & 63) == 0) lds[tid >> 6] = cnt;
    __syncthreads();
    if (tid == 0) blockSums[blockIdx.x] = lds[0] + lds[1] + lds[2] + lds[3];
}

// Single-block exclusive scan of blockSums (numBlocks <= SCAN_THREADS*SCAN_VPT).
__global__ void k_scan(int* __restrict__ sums, int numBlocks,
                       int* __restrict__ countOut, float* __restrict__ countOutF) {
    __shared__ int lds[32];
    const int tid  = threadIdx.x;
    const int lane = tid & 63;
    const int wave = tid >> 6;   // 16 waves

    int vals[SCAN_VPT];
    const int base = tid * SCAN_VPT;
    int local = 0;
#pragma unroll
    for (int j = 0; j < SCAN_VPT; ++j) {
        const int i = base + j;
        const int v = (i < numBlocks) ? sums[i] : 0;
        vals[j] = local;         // thread-local exclusive
        local += v;
    }
    int incl = local;
#pragma unroll
    for (int off = 1; off < 64; off <<= 1) {
        const int y = __shfl_up(incl, off, 64);
        if (lane >= off) incl += y;
    }
    if (lane == 63) lds[wave] = incl;
    __syncthreads();
    if (wave == 0 && lane < 16) {
        int w = lds[lane];
#pragma unroll
        for (int off = 1; off < 16; off <<= 1) {
            const int y = __shfl_up(w, off, 16);
            if ((lane & 15) >= off) w += y;
        }
        lds[16 + lane] = w;      // inclusive wave prefix
    }
    __syncthreads();
    const int waveEx   = (wave == 0) ? 0 : lds[16 + wave - 1];
    const int threadEx = waveEx + incl - local;
#pragma unroll
    for (int j = 0; j < SCAN_VPT; ++j) {
        const int i = base + j;
        if (i < numBlocks) sums[i] = threadEx + vals[j];
    }
    if (tid == SCAN_THREADS - 1) {
        const int total = waveEx + incl;
        *countOut  = total;
        *countOutF = (float)total;
    }
}

// exclusive block scan over 256 threads (4 waves); returns exclusive rank,
// sets *blockTotal. lds must have >= 9 ints.
__device__ __forceinline__ int block_scan_excl_256(int val, int* lds, int* blockTotal) {
    const int tid  = threadIdx.x;
    const int lane = tid & 63;
    const int wave = tid >> 6;
    int incl = val;
#pragma unroll
    for (int off = 1; off < 64; off <<= 1) {
        const int y = __shfl_up(incl, off, 64);
        if (lane >= off) incl += y;
    }
    if (lane == 63) lds[wave] = incl;
    __syncthreads();
    if (tid == 0) {
        const int s0 = lds[0], s1 = lds[1], s2 = lds[2], s3 = lds[3];
        lds[4] = 0; lds[5] = s0; lds[6] = s0 + s1; lds[7] = s0 + s1 + s2;
        lds[8] = s0 + s1 + s2 + s3;
    }
    __syncthreads();
    const int ex = lds[4 + wave] + incl - val;
    *blockTotal = lds[8];
    return ex;
}

__global__ void k_scatter(const float* __restrict__ x, int n,
                          const int* __restrict__ blockOffsets, float* __restrict__ y) {
    __shared__ float vals[CHUNK];   // 16 KB staging
    __shared__ int scan_lds[9];
    const int tid = threadIdx.x;
    const long long tbase = (long long)blockIdx.x * CHUNK + tid * VPT;

    float v[VPT];
    if (tbase + VPT <= n) {
#pragma unroll
        for (int k = 0; k < 4; ++k) {
            const float4 f = *reinterpret_cast<const float4*>(x + tbase + 4 * k);
            v[4 * k + 0] = f.x; v[4 * k + 1] = f.y; v[4 * k + 2] = f.z; v[4 * k + 3] = f.w;
        }
    } else {
#pragma unroll
        for (int j = 0; j < VPT; ++j)
            v[j] = (tbase + j < n) ? x[tbase + j] : 0.f;
    }

    int c = 0;
#pragma unroll
    for (int j = 0; j < VPT; ++j) c += (v[j] > 0.f);

    int total;
    int r = block_scan_excl_256(c, scan_lds, &total);

#pragma unroll
    for (int j = 0; j < VPT; ++j) {
        if (v[j] > 0.f) vals[r++] = v[j];
    }
    __syncthreads();

    const int offset = blockOffsets[blockIdx.x];
    for (int j = tid; j < total; j += BLOCK) {
        y[offset + j] = vals[j];
    }
}

__global__ void k_zerofill(float* __restrict__ y, const int* __restrict__ count, int n) {
    const long long i = ((long long)blockIdx.x * BLOCK + threadIdx.x) * 4;
    if (i >= n) return;
    const int c = *count;
    if (i + 4 <= c) return;                      // fully inside valid region
    const long long start = (i > c) ? i : c;
    const long long end   = (i + 4 < n) ? i + 4 : n;
    if (start == i && end == i + 4) {
        *reinterpret_cast<float4*>(y + i) = make_float4(0.f, 0.f, 0.f, 0.f);
    } else {
        for (long long j = start; j < end; ++j) y[j] = 0.f;
    }
}

extern "C" void kernel_launch(void* const* d_in, const int* in_sizes, int n_in,
                              void* d_out, int out_size, void* d_ws, size_t ws_size,
                              hipStream_t stream) {
    const float* x = (const float*)d_in[0];
    float* y = (float*)d_out;
    const int n = in_sizes[0];

    int* blockSums = (int*)d_ws;
    const int numBlocks = (n + CHUNK - 1) / CHUNK;   // 16384 for N=64M
    int* countPtr = blockSums + numBlocks;

    k_count<<<numBlocks, BLOCK, 0, stream>>>(x, n, blockSums);
    k_scan<<<1, SCAN_THREADS, 0, stream>>>(blockSums, numBlocks,
                                           countPtr, y + (out_size - 1));
    k_scatter<<<numBlocks, BLOCK, 0, stream>>>(x, n, blockSums, y);
    const int zfBlocks = ((n + 3) / 4 + BLOCK - 1) / BLOCK;
    k_zerofill<<<zfBlocks, BLOCK, 0, stream>>>(y, countPtr, n);
}